// Round 6
// baseline (546.336 us; speedup 1.0000x reference)
//
#include <hip/hip_runtime.h>

#define N_NODES 100000
#define IN_DIM  256
#define HID_DIM 128
#define OUT_DIM 237

#define BSH   9                      // bucket = dst >> 9  (512 nodes/bucket)
#define NBKT  196                    // ceil(100000 / 512)
#define BNODE 512

typedef __attribute__((ext_vector_type(8))) short bf16x8;
typedef __attribute__((ext_vector_type(4))) float fx4;
typedef __attribute__((ext_vector_type(8))) _Float16 h8;

// ---------------- coarse bucket histogram (NO per-node global atomics) ----------------
__global__ __launch_bounds__(256) void k_bhist(const int* __restrict__ dst,
                                               int* __restrict__ bcnt, int E) {
    __shared__ int h[NBKT];
    for (int i = threadIdx.x; i < NBKT; i += 256) h[i] = 0;
    __syncthreads();
    const int base = blockIdx.x * 8192;
    for (int it = 0; it < 32; ++it) {
        int e = base + it * 256 + threadIdx.x;
        if (e < E) atomicAdd(&h[dst[e] >> BSH], 1);
    }
    __syncthreads();
    for (int i = threadIdx.x; i < NBKT; i += 256)
        if (h[i]) atomicAdd(&bcnt[i], h[i]);
}

// exclusive scan of bucket counts (NBKT <= 256), single block
__global__ void k_bscan(const int* __restrict__ bcnt, int* __restrict__ gbase,
                        int* __restrict__ gcur, int E) {
    __shared__ int lds[256];
    int tid = threadIdx.x;
    int v = (tid < NBKT) ? bcnt[tid] : 0;
    lds[tid] = v;
    __syncthreads();
    for (int off = 1; off < 256; off <<= 1) {
        int t = (tid >= off) ? lds[tid - off] : 0;
        __syncthreads();
        lds[tid] += t;
        __syncthreads();
    }
    int excl = lds[tid] - v;
    if (tid < NBKT) { gbase[tid] = excl; gcur[tid] = excl; }
    if (tid == 0) gbase[NBKT] = E;
}

// ---------------- pass 1: partition (src,dst) pairs into coarse buckets ----------------
__global__ __launch_bounds__(256) void k_part1(const int* __restrict__ src,
                                               const int* __restrict__ dst,
                                               int* __restrict__ gcur,
                                               int2* __restrict__ pairs, int E) {
    __shared__ int h[NBKT];
    __shared__ int base[NBKT];
    const int tid = threadIdx.x;
    for (int i = tid; i < NBKT; i += 256) h[i] = 0;
    __syncthreads();
    const int cbase = blockIdx.x * 8192;
    for (int it = 0; it < 32; ++it) {
        int e = cbase + it * 256 + tid;
        if (e < E) atomicAdd(&h[dst[e] >> BSH], 1);
    }
    __syncthreads();
    for (int i = tid; i < NBKT; i += 256) {
        int c = h[i];
        base[i] = c ? atomicAdd(&gcur[i], c) : 0;
    }
    __syncthreads();
    for (int i = tid; i < NBKT; i += 256) h[i] = 0;
    __syncthreads();
    for (int it = 0; it < 32; ++it) {
        int e = cbase + it * 256 + tid;
        if (e < E) {
            int d = dst[e];
            int b = d >> BSH;
            int pos = base[b] + atomicAdd(&h[b], 1);
            pairs[pos] = make_int2(src[e], d);
        }
    }
}

// ---------------- per-bucket CSR build: count + local scan + rp/dinv + scatter ss ----
__global__ __launch_bounds__(256) void k_bucket_csr(const int2* __restrict__ pairs,
                                                    const int* __restrict__ gbase,
                                                    int* __restrict__ rp,
                                                    float* __restrict__ dinv,
                                                    int* __restrict__ ss, int n, int E) {
    __shared__ int cnt[BNODE];
    __shared__ int excl[BNODE];
    __shared__ int sbuf[256];
    const int b = blockIdx.x;
    const int n0 = b << BSH;
    const int tid = threadIdx.x;
    for (int i = tid; i < BNODE; i += 256) cnt[i] = 0;
    __syncthreads();
    const int beg = gbase[b], end = gbase[b + 1];
    for (int i = beg + tid; i < end; i += 256)
        atomicAdd(&cnt[pairs[i].y - n0], 1);
    __syncthreads();
    int c0 = cnt[2 * tid], c1 = cnt[2 * tid + 1];
    int s = c0 + c1;
    sbuf[tid] = s;
    __syncthreads();
    for (int off = 1; off < 256; off <<= 1) {
        int t = (tid >= off) ? sbuf[tid - off] : 0;
        __syncthreads();
        sbuf[tid] += t;
        __syncthreads();
    }
    int e0 = sbuf[tid] - s;
    excl[2 * tid] = e0;
    excl[2 * tid + 1] = e0 + c0;
    __syncthreads();
    for (int i = tid; i < BNODE; i += 256) {
        int node = n0 + i;
        if (node < n) {
            rp[node] = beg + excl[i];
            dinv[node] = rsqrtf((float)cnt[i] + 1.0f);   // +1 self-loop
        }
    }
    __syncthreads();
    for (int i = tid; i < BNODE; i += 256) cnt[i] = beg + excl[i];  // cursors
    __syncthreads();
    for (int i = beg + tid; i < end; i += 256) {
        int2 p = pairs[i];
        int pos = atomicAdd(&cnt[p.y - n0], 1);
        ss[pos] = p.x;
    }
    if (b == 0 && tid == 0) rp[n] = E;
}

// ---------------- W hi/lo bf16 split into b-fragment layout [k/8][col][k%8] ----------------
// hi = bit-truncated bf16(v); lo = bf16(v - hi). Residual <= 2^-16 * |v|.
__global__ __launch_bounds__(256) void k_wsplit(const float* __restrict__ W,
                                                unsigned short* __restrict__ Wh,
                                                unsigned short* __restrict__ Wl,
                                                int K, int C, int CD) {
    int t = blockIdx.x * 256 + threadIdx.x;
    if (t >= K * CD) return;
    int k = t / CD, c = t - k * CD;
    float v = (c < C) ? W[k * C + c] : 0.f;
    unsigned u = __float_as_uint(v);
    unsigned short hi = (unsigned short)(u >> 16);
    float lof = v - __uint_as_float(u & 0xffff0000u);
    unsigned short lo = (unsigned short)(__float_as_uint(lof) >> 16);
    int d = ((k >> 3) * CD + c) * 8 + (k & 7);
    Wh[d] = hi;
    Wl[d] = lo;
}

// ---------------- bf16x3 split-precision MFMA GEMM, B staged in LDS -------------------
// Block: 128 rows x 128 cols, 4 waves stacked over rows (32 rows/wave).
// r6 change: ALL B-fragments for this block's 128 cols live in LDS (one barrier,
// none in the loop) so the K-loop's only VMEM is the 4 A-loads, prefetched one
// iter ahead into registers (vmcnt wait lands AFTER the MFMA cluster). B reads
// are ds_read_b128, conflict-free (each 16-lane group reads a contiguous 256B).
// LDS: 128 KB (K=256) / 64 KB (K=128). A is fp32 or fp16 (fp16 split is EXACT).
// v_mfma_f32_16x16x32_bf16 layouts (m89-verified):
//   A: row=lane&15, k=8*(lane>>4)+i   B: col=lane&15, same k
//   D: col=lane&15, row=4*(lane>>4)+reg
template <typename AT, typename OT, int K, int CD, int SCALE, int BIAS>
__global__ __launch_bounds__(256) void k_gemm_mfma(const AT* __restrict__ A,
                                                   const unsigned short* __restrict__ Bh,
                                                   const unsigned short* __restrict__ Bl,
                                                   const float* __restrict__ dinv,
                                                   const float* __restrict__ bias,
                                                   OT* __restrict__ out,
                                                   int ldo, int ncol) {
    constexpr int NS = K / 32;
    constexpr int NSLOT = (K / 8) * 2 * 128;        // bf16x8 slots: [kb][hl][c]
    __shared__ bf16x8 Blds[NSLOT];

    const int tid = threadIdx.x;
    const int lane = tid & 63;
    const int w = tid >> 6;
    const int l15 = lane & 15;
    const int lq = lane >> 4;                       // 0..3
    const int rowbase = blockIdx.x * 128 + w * 32;
    const int col0 = blockIdx.y * 128;

    const bf16x8* __restrict__ Bh8 = (const bf16x8*)Bh;
    const bf16x8* __restrict__ Bl8 = (const bf16x8*)Bl;

    // stage B fragments for cols [col0, col0+128) into LDS (coalesced 16B copies)
    for (int idx = tid; idx < NSLOT; idx += 256) {
        int c = idx & 127;
        int hl = (idx >> 7) & 1;
        int kb = idx >> 8;
        Blds[idx] = (hl ? Bl8 : Bh8)[kb * CD + col0 + c];
    }
    __syncthreads();

    // k-invariant row clamp + base pointers (clamped rows read garbage; stores masked)
    int r0 = rowbase + l15;      if (r0 > N_NODES - 1) r0 = N_NODES - 1;
    int r1 = rowbase + 16 + l15; if (r1 > N_NODES - 1) r1 = N_NODES - 1;
    const AT* ap0 = A + (size_t)r0 * K + lq * 8;
    const AT* ap1 = A + (size_t)r1 * K + lq * 8;

    fx4 acc[2][8] = {};
    float af[2][8];

#define LDA(dst_, ptr_, ks_)                                              \
    do {                                                                  \
        const AT* p_ = (ptr_) + (ks_) * 32;                               \
        if constexpr (sizeof(AT) == 4) {                                  \
            float4 f0_ = *(const float4*)p_;                              \
            float4 f1_ = *(const float4*)(p_ + 4);                        \
            dst_[0] = f0_.x; dst_[1] = f0_.y; dst_[2] = f0_.z;            \
            dst_[3] = f0_.w; dst_[4] = f1_.x; dst_[5] = f1_.y;            \
            dst_[6] = f1_.z; dst_[7] = f1_.w;                             \
        } else {                                                          \
            h8 v_ = *(const h8*)p_;                                       \
            _Pragma("unroll")                                             \
            for (int i_ = 0; i_ < 8; ++i_) dst_[i_] = (float)v_[i_];      \
        }                                                                 \
    } while (0)

    LDA(af[0], ap0, 0);
    LDA(af[1], ap1, 0);

    for (int ks = 0; ks < NS; ++ks) {               // rolled (r2 codegen best)
        float fn[2][8];
        if (ks + 1 < NS) {                          // issue next A-loads early
            LDA(fn[0], ap0, ks + 1);
            LDA(fn[1], ap1, ks + 1);
        }
        bf16x8 ah[2], al[2];
#pragma unroll
        for (int rf = 0; rf < 2; ++rf)
#pragma unroll
            for (int i = 0; i < 8; ++i) {
                float fv = af[rf][i];
                unsigned u = __float_as_uint(fv);
                ah[rf][i] = (short)(u >> 16);
                float lof = fv - __uint_as_float(u & 0xffff0000u);
                al[rf][i] = (short)(__float_as_uint(lof) >> 16);
            }
        const int kb = ks * 4 + lq;
#pragma unroll
        for (int cf = 0; cf < 8; ++cf) {
            bf16x8 bh = Blds[(kb * 2 + 0) * 128 + cf * 16 + l15];
            bf16x8 bl = Blds[(kb * 2 + 1) * 128 + cf * 16 + l15];
#pragma unroll
            for (int rf = 0; rf < 2; ++rf) {
                acc[rf][cf] = __builtin_amdgcn_mfma_f32_16x16x32_bf16(ah[rf], bh, acc[rf][cf], 0, 0, 0);
                acc[rf][cf] = __builtin_amdgcn_mfma_f32_16x16x32_bf16(ah[rf], bl, acc[rf][cf], 0, 0, 0);
                acc[rf][cf] = __builtin_amdgcn_mfma_f32_16x16x32_bf16(al[rf], bh, acc[rf][cf], 0, 0, 0);
            }
        }
        if (ks + 1 < NS) {                          // vmcnt wait lands here, post-MFMA
#pragma unroll
            for (int rf = 0; rf < 2; ++rf)
#pragma unroll
                for (int i = 0; i < 8; ++i) af[rf][i] = fn[rf][i];
        }
    }
#undef LDA

    float bb[8];
#pragma unroll
    for (int cf = 0; cf < 8; ++cf) {
        int c = col0 + cf * 16 + l15;
        bb[cf] = (BIAS && c < ncol) ? bias[c] : 0.f;
    }

#pragma unroll
    for (int rf = 0; rf < 2; ++rf) {
#pragma unroll
        for (int r = 0; r < 4; ++r) {
            const int row = rowbase + rf * 16 + lq * 4 + r;
            if (row < N_NODES) {
                const float s = SCALE ? dinv[row] : 1.f;
#pragma unroll
                for (int cf = 0; cf < 8; ++cf) {
                    const int c = col0 + cf * 16 + l15;
                    if (c < ncol) {
                        float v = acc[rf][cf][r];
                        if (SCALE) v *= s;
                        if (BIAS) v += bb[cf];
                        out[(size_t)row * ldo + c] = (OT)v;
                    }
                }
            }
        }
    }
}

// ---------------- CSR aggregation over fp16 table, fp32 accumulate ----------------
// 16 lanes per node, 16B (8 halves) per lane per edge.
template <int RELU, typename OT>
__global__ __launch_bounds__(256) void k_agg_csr(const _Float16* __restrict__ tab,
                                                 const int* __restrict__ rp,
                                                 const int* __restrict__ ss,
                                                 const float* __restrict__ dinv,
                                                 const float* __restrict__ bias,
                                                 OT* __restrict__ outp, int n) {
    int t = blockIdx.x * 256 + threadIdx.x;
    int node = t >> 4;
    int q = (t & 15) * 8;                 // half index within the 128-wide row
    if (node >= n) return;
    int beg = rp[node], end = rp[node + 1];
    float a[8] = {};
    int i = beg;
    for (; i + 2 <= end; i += 2) {
        int s0 = ss[i], s1 = ss[i + 1];
        h8 v0 = *(const h8*)(tab + (size_t)s0 * HID_DIM + q);
        h8 v1 = *(const h8*)(tab + (size_t)s1 * HID_DIM + q);
#pragma unroll
        for (int j = 0; j < 8; ++j) a[j] += (float)v0[j] + (float)v1[j];
    }
    if (i < end) {
        int s0 = ss[i];
        h8 v0 = *(const h8*)(tab + (size_t)s0 * HID_DIM + q);
#pragma unroll
        for (int j = 0; j < 8; ++j) a[j] += (float)v0[j];
    }
    h8 own = *(const h8*)(tab + (size_t)node * HID_DIM + q);
    float s = dinv[node];
    if constexpr (RELU) {
        float4 b0 = *(const float4*)(bias + q);
        float4 b1 = *(const float4*)(bias + q + 4);
        float bb[8] = {b0.x, b0.y, b0.z, b0.w, b1.x, b1.y, b1.z, b1.w};
        h8 r;
#pragma unroll
        for (int j = 0; j < 8; ++j)
            r[j] = (_Float16)(fmaxf(fmaf(s, a[j] + (float)own[j], bb[j]), 0.f) * s);
        *(h8*)((_Float16*)outp + (size_t)node * HID_DIM + q) = r;
    } else if constexpr (sizeof(OT) == 2) {
        h8 r;
#pragma unroll
        for (int j = 0; j < 8; ++j) r[j] = (_Float16)(s * (a[j] + (float)own[j]));
        *(h8*)((_Float16*)outp + (size_t)node * HID_DIM + q) = r;
    } else {
        float* op = (float*)outp + (size_t)node * HID_DIM + q;
        float4 r0, r1;
        r0.x = s * (a[0] + (float)own[0]);
        r0.y = s * (a[1] + (float)own[1]);
        r0.z = s * (a[2] + (float)own[2]);
        r0.w = s * (a[3] + (float)own[3]);
        r1.x = s * (a[4] + (float)own[4]);
        r1.y = s * (a[5] + (float)own[5]);
        r1.z = s * (a[6] + (float)own[6]);
        r1.w = s * (a[7] + (float)own[7]);
        *(float4*)op = r0;
        *(float4*)(op + 4) = r1;
    }
}

// ---------------- GEMM2 fp32 fallback (used only if ws too small for W2 frags) ----------------
__global__ __launch_bounds__(256) void k_gemm2(const float* __restrict__ A2,
                                               const float* __restrict__ W2,
                                               const float* __restrict__ b2,
                                               float* __restrict__ out) {
    __shared__ float As[16 * 132];
    __shared__ float Bs[16 * 128];
    const int tid = threadIdx.x;
    const int tx = tid & 15, ty = tid >> 4;
    const int row0 = blockIdx.x * 128;
    const int col0 = blockIdx.y * 128;

    const int ar = tid >> 2;
    const int ak = (tid & 3) * 4;
    const int bk = tid >> 5;
    const int bc = (tid & 31) * 4;

    float acc[8][8] = {};

    for (int k0 = 0; k0 < HID_DIM; k0 += 16) {
        float4 a0 = make_float4(0.f, 0.f, 0.f, 0.f), a1 = a0;
        const int r0 = row0 + ar, r1 = row0 + ar + 64;
        if (r0 < N_NODES) a0 = *(const float4*)(A2 + (size_t)r0 * HID_DIM + k0 + ak);
        if (r1 < N_NODES) a1 = *(const float4*)(A2 + (size_t)r1 * HID_DIM + k0 + ak);
        float bv0[4], bv1[4];
#pragma unroll
        for (int j = 0; j < 4; ++j) {
            int c = col0 + bc + j;
            bv0[j] = (c < OUT_DIM) ? W2[(size_t)(k0 + bk) * OUT_DIM + c] : 0.f;
            bv1[j] = (c < OUT_DIM) ? W2[(size_t)(k0 + bk + 8) * OUT_DIM + c] : 0.f;
        }
        __syncthreads();
        As[(ak + 0) * 132 + ar] = a0.x;
        As[(ak + 1) * 132 + ar] = a0.y;
        As[(ak + 2) * 132 + ar] = a0.z;
        As[(ak + 3) * 132 + ar] = a0.w;
        As[(ak + 0) * 132 + ar + 64] = a1.x;
        As[(ak + 1) * 132 + ar + 64] = a1.y;
        As[(ak + 2) * 132 + ar + 64] = a1.z;
        As[(ak + 3) * 132 + ar + 64] = a1.w;
#pragma unroll
        for (int j = 0; j < 4; ++j) {
            Bs[bk * 128 + bc + j] = bv0[j];
            Bs[(bk + 8) * 128 + bc + j] = bv1[j];
        }
        __syncthreads();
#pragma unroll
        for (int kk = 0; kk < 16; ++kk) {
            float4 A0 = *(const float4*)(As + kk * 132 + ty * 4);
            float4 A1 = *(const float4*)(As + kk * 132 + 64 + ty * 4);
            float4 B0 = *(const float4*)(Bs + kk * 128 + tx * 4);
            float4 B1 = *(const float4*)(Bs + kk * 128 + 64 + tx * 4);
            float a_[8] = {A0.x, A0.y, A0.z, A0.w, A1.x, A1.y, A1.z, A1.w};
            float b_[8] = {B0.x, B0.y, B0.z, B0.w, B1.x, B1.y, B1.z, B1.w};
#pragma unroll
            for (int i = 0; i < 8; ++i)
#pragma unroll
                for (int j = 0; j < 8; ++j)
                    acc[i][j] = fmaf(a_[i], b_[j], acc[i][j]);
        }
    }
#pragma unroll
    for (int i = 0; i < 8; ++i) {
        const int r = row0 + ty * 4 + (i & 3) + (i >> 2) * 64;
        if (r < N_NODES) {
#pragma unroll
            for (int j = 0; j < 8; ++j) {
                int c = col0 + tx * 4 + (j & 3) + (j >> 2) * 64;
                if (c < OUT_DIM) out[(size_t)r * OUT_DIM + c] = acc[i][j] + b2[c];
            }
        }
    }
}

extern "C" void kernel_launch(void* const* d_in, const int* in_sizes, int n_in,
                              void* d_out, int out_size, void* d_ws, size_t ws_size,
                              hipStream_t stream) {
    const float* x  = (const float*)d_in[0];
    const int*   ei = (const int*)d_in[1];
    const float* W1 = (const float*)d_in[2];
    const float* b1 = (const float*)d_in[3];
    const float* W2 = (const float*)d_in[4];
    const float* b2 = (const float*)d_in[5];
    float* out = (float*)d_out;

    const int E = in_sizes[1] / 2;
    const int* src = ei;
    const int* dst = ei + E;

    // ws: hs (layer-1 fp16 features, 25.6 MB) / A2 alias at base.
    _Float16* hs = (_Float16*)d_ws;
    _Float16* A2h = hs;
    float* A2f = (float*)d_ws;                         // fp32 fallback only

    // d_out scratch (all dead before the final out-writer):
    char* ob = (char*)d_out;
    size_t o = (size_t)N_NODES * HID_DIM * 2;          // h2 fp16: 25.6 MB
    _Float16* h2 = (_Float16*)ob;
    float* dinv = (float*)(ob + o); o += 400128;
    int* bcnt = (int*)(ob + o); o += 1024;             // NBKT ints
    int* rp   = (int*)(ob + o); o += 400640;           // (N+1) ints padded
    int* gbase = (int*)(ob + o); o += 1024;            // NBKT+1 ints
    int* gcur  = (int*)(ob + o); o += 1024;
    int* ss   = (int*)(ob + o); o += (size_t)E * 4;    // 6.4 MB
    int2* pairs = (int2*)(ob + o); o += (size_t)E * 8; // 12.8 MB
    // W1 fragments: dead before the final out-writes (only read by gemm1)
    unsigned short* W1h = (unsigned short*)(ob + o); o += 65536;
    unsigned short* W1l = (unsigned short*)(ob + o); o += 65536;

    // W2 fragments MUST NOT live in d_out (gemm2 reads them while writing out).
    const size_t W2OFF = 32u << 20;
    const bool w2frag = ws_size >= W2OFF + 131072;
    unsigned short* W2h = (unsigned short*)((char*)d_ws + W2OFF);
    unsigned short* W2l = W2h + 32768;

    const int NB1 = (E + 8191) / 8192;                 // 196

    k_wsplit<<<128, 256, 0, stream>>>(W1, W1h, W1l, IN_DIM, HID_DIM, HID_DIM);
    if (w2frag)
        k_wsplit<<<128, 256, 0, stream>>>(W2, W2h, W2l, HID_DIM, OUT_DIM, 256);

    hipMemsetAsync(bcnt, 0, 1024, stream);
    k_bhist<<<NB1, 256, 0, stream>>>(dst, bcnt, E);
    k_bscan<<<1, 256, 0, stream>>>(bcnt, gbase, gcur, E);
    k_part1<<<NB1, 256, 0, stream>>>(src, dst, gcur, pairs, E);
    k_bucket_csr<<<NBKT, 256, 0, stream>>>(pairs, gbase, rp, dinv, ss, N_NODES, E);

    // GEMM1: hs = (X @ W1) * dinv[row]  — bf16x3 MFMA, B in LDS, fp16 output
    dim3 g1((N_NODES + 127) / 128, 1);
    k_gemm_mfma<float, _Float16, IN_DIM, HID_DIM, 1, 0><<<g1, 256, 0, stream>>>(
        x, W1h, W1l, dinv, nullptr, hs, HID_DIM, HID_DIM);

    const int aggBlocks = (N_NODES * 16 + 255) / 256;
    k_agg_csr<1, _Float16><<<aggBlocks, 256, 0, stream>>>(hs, rp, ss, dinv, b1, h2, N_NODES);

    if (w2frag) {
        k_agg_csr<0, _Float16><<<aggBlocks, 256, 0, stream>>>(h2, rp, ss, dinv, b1, A2h, N_NODES);
        // GEMM2: out = A2 @ W2 + b2 — bf16x3 MFMA (fp16 A splits exactly), cols padded to 256
        dim3 g2((N_NODES + 127) / 128, 2);
        k_gemm_mfma<_Float16, float, HID_DIM, 256, 0, 1><<<g2, 256, 0, stream>>>(
            A2h, W2h, W2l, nullptr, b2, out, OUT_DIM, OUT_DIM);
    } else {
        k_agg_csr<0, float><<<aggBlocks, 256, 0, stream>>>(h2, rp, ss, dinv, b1, A2f, N_NODES);
        dim3 g2((N_NODES + 127) / 128, (OUT_DIM + 127) / 128);
        k_gemm2<<<g2, 256, 0, stream>>>(A2f, W2, b2, out);
    }
}

// Round 8
// 478.047 us; speedup vs baseline: 1.1428x; 1.1428x over previous
//
#include <hip/hip_runtime.h>

#define N_NODES 100000
#define IN_DIM  256
#define HID_DIM 128
#define OUT_DIM 237

#define BSH   9                      // bucket = dst >> 9  (512 nodes/bucket)
#define NBKT  196                    // ceil(100000 / 512)
#define BNODE 512
#define EPB   4096                   // edges per partition block

typedef __attribute__((ext_vector_type(8))) short bf16x8;
typedef __attribute__((ext_vector_type(4))) float fx4;
typedef __attribute__((ext_vector_type(8))) _Float16 h8;

// ---------------- bucket histogram; saves per-block rows for k_part1 reuse ----------
__global__ __launch_bounds__(256) void k_bhist(const int* __restrict__ dst,
                                               int* __restrict__ bcnt,
                                               int* __restrict__ hcnt, int E) {
    __shared__ int h[NBKT];
    for (int i = threadIdx.x; i < NBKT; i += 256) h[i] = 0;
    __syncthreads();
    const int base = blockIdx.x * EPB;
    for (int it = 0; it < EPB / 256; ++it) {
        int e = base + it * 256 + threadIdx.x;
        if (e < E) atomicAdd(&h[dst[e] >> BSH], 1);
    }
    __syncthreads();
    int* hrow = hcnt + blockIdx.x * NBKT;
    for (int i = threadIdx.x; i < NBKT; i += 256) {
        int c = h[i];
        hrow[i] = c;
        if (c) atomicAdd(&bcnt[i], c);
    }
}

// exclusive scan of bucket counts (NBKT <= 256), single block
__global__ void k_bscan(const int* __restrict__ bcnt, int* __restrict__ gbase,
                        int* __restrict__ gcur, int E) {
    __shared__ int lds[256];
    int tid = threadIdx.x;
    int v = (tid < NBKT) ? bcnt[tid] : 0;
    lds[tid] = v;
    __syncthreads();
    for (int off = 1; off < 256; off <<= 1) {
        int t = (tid >= off) ? lds[tid - off] : 0;
        __syncthreads();
        lds[tid] += t;
        __syncthreads();
    }
    int excl = lds[tid] - v;
    if (tid < NBKT) { gbase[tid] = excl; gcur[tid] = excl; }
    if (tid == 0) gbase[NBKT] = E;
}

// ---------------- partition: reserve from saved histogram, scatter packed pairs ------
// pair word = (src << 9) | (dst & 511): src < 2^17, local dst < 512 -> 26 bits.
__global__ __launch_bounds__(256) void k_part1(const int* __restrict__ src,
                                               const int* __restrict__ dst,
                                               const int* __restrict__ hcnt,
                                               int* __restrict__ gcur,
                                               unsigned* __restrict__ pairs, int E) {
    __shared__ int h[NBKT];
    __shared__ int base[NBKT];
    const int tid = threadIdx.x;
    const int* hrow = hcnt + blockIdx.x * NBKT;
    for (int i = tid; i < NBKT; i += 256) {
        int c = hrow[i];
        base[i] = c ? atomicAdd(&gcur[i], c) : 0;
        h[i] = 0;
    }
    __syncthreads();
    const int cbase = blockIdx.x * EPB;
    for (int it = 0; it < EPB / 256; ++it) {
        int e = cbase + it * 256 + tid;
        if (e < E) {
            int d = dst[e];
            int b = d >> BSH;
            int pos = base[b] + atomicAdd(&h[b], 1);
            pairs[pos] = ((unsigned)src[e] << BSH) | (unsigned)(d & (BNODE - 1));
        }
    }
}

// ---------------- per-bucket CSR build: count + local scan + rp/dinv + scatter ss ----
__global__ __launch_bounds__(256) void k_bucket_csr(const unsigned* __restrict__ pairs,
                                                    const int* __restrict__ gbase,
                                                    int* __restrict__ rp,
                                                    float* __restrict__ dinv,
                                                    int* __restrict__ ss, int n, int E) {
    __shared__ int cnt[BNODE];
    __shared__ int excl[BNODE];
    __shared__ int sbuf[256];
    const int b = blockIdx.x;
    const int n0 = b << BSH;
    const int tid = threadIdx.x;
    for (int i = tid; i < BNODE; i += 256) cnt[i] = 0;
    __syncthreads();
    const int beg = gbase[b], end = gbase[b + 1];
    for (int i = beg + tid; i < end; i += 256)
        atomicAdd(&cnt[pairs[i] & (BNODE - 1)], 1);
    __syncthreads();
    int c0 = cnt[2 * tid], c1 = cnt[2 * tid + 1];
    int s = c0 + c1;
    sbuf[tid] = s;
    __syncthreads();
    for (int off = 1; off < 256; off <<= 1) {
        int t = (tid >= off) ? sbuf[tid - off] : 0;
        __syncthreads();
        sbuf[tid] += t;
        __syncthreads();
    }
    int e0 = sbuf[tid] - s;
    excl[2 * tid] = e0;
    excl[2 * tid + 1] = e0 + c0;
    __syncthreads();
    for (int i = tid; i < BNODE; i += 256) {
        int node = n0 + i;
        if (node < n) {
            rp[node] = beg + excl[i];
            dinv[node] = rsqrtf((float)cnt[i] + 1.0f);   // +1 self-loop
        }
    }
    __syncthreads();
    for (int i = tid; i < BNODE; i += 256) cnt[i] = beg + excl[i];  // cursors
    __syncthreads();
    for (int i = beg + tid; i < end; i += 256) {
        unsigned p = pairs[i];
        int pos = atomicAdd(&cnt[p & (BNODE - 1)], 1);
        ss[pos] = (int)(p >> BSH);
    }
    if (b == 0 && tid == 0) rp[n] = E;
}

// ---------------- W hi/lo bf16 split into b-fragment layout [k/8][col][k%8] ----------------
// hi = bit-truncated bf16(v); lo = bf16(v - hi). Residual <= 2^-16 * |v|.
__global__ __launch_bounds__(256) void k_wsplit(const float* __restrict__ W,
                                                unsigned short* __restrict__ Wh,
                                                unsigned short* __restrict__ Wl,
                                                int K, int C, int CD) {
    int t = blockIdx.x * 256 + threadIdx.x;
    if (t >= K * CD) return;
    int k = t / CD, c = t - k * CD;
    float v = (c < C) ? W[k * C + c] : 0.f;
    unsigned u = __float_as_uint(v);
    unsigned short hi = (unsigned short)(u >> 16);
    float lof = v - __uint_as_float(u & 0xffff0000u);
    unsigned short lo = (unsigned short)(__float_as_uint(lof) >> 16);
    int d = ((k >> 3) * CD + c) * 8 + (k & 7);
    Wh[d] = hi;
    Wl[d] = lo;
}

// ---------------- bf16x3 split-precision MFMA GEMM (r2 config: FROZEN) ---------------
// Block: 128 rows x 128 cols, 4 waves stacked over rows (32 rows/wave).
// Rolling runtime K-loop, no LDS, no barriers — measured best (73us gemm1).
// Failed variants: full unroll+prefetch (r3, 94us), 64-row tile (r4, 87us),
// B-in-LDS 128KB (r6, 130us: occupancy 15.5->8.7%). Do not re-try without new evidence.
// A is fp32 or fp16 (fp16 -> bf16 hi/lo split is EXACT).
// v_mfma_f32_16x16x32_bf16 layouts (m89-verified):
//   A: row=lane&15, k=8*(lane>>4)+i   B: col=lane&15, same k
//   D: col=lane&15, row=4*(lane>>4)+reg
template <typename AT, typename OT, int K, int CD, int SCALE, int BIAS>
__global__ __launch_bounds__(256) void k_gemm_mfma(const AT* __restrict__ A,
                                                   const unsigned short* __restrict__ Bh,
                                                   const unsigned short* __restrict__ Bl,
                                                   const float* __restrict__ dinv,
                                                   const float* __restrict__ bias,
                                                   OT* __restrict__ out,
                                                   int ldo, int ncol) {
    const int tid = threadIdx.x;
    const int lane = tid & 63;
    const int w = tid >> 6;
    const int l15 = lane & 15;
    const int lq = lane >> 4;                       // 0..3
    const int rowbase = blockIdx.x * 128 + w * 32;
    const int col0 = blockIdx.y * 128;

    const bf16x8* __restrict__ Bh8 = (const bf16x8*)Bh;
    const bf16x8* __restrict__ Bl8 = (const bf16x8*)Bl;

    fx4 acc[2][8] = {};

    for (int k0 = 0; k0 < K; k0 += 32) {
        bf16x8 ah[2], al[2];
#pragma unroll
        for (int rf = 0; rf < 2; ++rf) {
            int row = rowbase + rf * 16 + l15;
            if (row > N_NODES - 1) row = N_NODES - 1;   // clamp: garbage ok, stores masked
            const AT* ap = A + (size_t)row * K + k0 + lq * 8;
            float f[8];
            if constexpr (sizeof(AT) == 4) {
                float4 f0 = *(const float4*)ap;
                float4 f1 = *(const float4*)(ap + 4);
                f[0] = f0.x; f[1] = f0.y; f[2] = f0.z; f[3] = f0.w;
                f[4] = f1.x; f[5] = f1.y; f[6] = f1.z; f[7] = f1.w;
            } else {
                h8 v = *(const h8*)ap;
#pragma unroll
                for (int i = 0; i < 8; ++i) f[i] = (float)v[i];
            }
#pragma unroll
            for (int i = 0; i < 8; ++i) {
                unsigned u = __float_as_uint(f[i]);
                ah[rf][i] = (short)(u >> 16);
                float lof = f[i] - __uint_as_float(u & 0xffff0000u);
                al[rf][i] = (short)(__float_as_uint(lof) >> 16);
            }
        }
        const int kb = (k0 >> 3) + lq;
#pragma unroll
        for (int cf = 0; cf < 8; ++cf) {
            const int bi = kb * CD + col0 + cf * 16 + l15;
            bf16x8 bh = Bh8[bi];
            bf16x8 bl = Bl8[bi];
#pragma unroll
            for (int rf = 0; rf < 2; ++rf) {
                acc[rf][cf] = __builtin_amdgcn_mfma_f32_16x16x32_bf16(ah[rf], bh, acc[rf][cf], 0, 0, 0);
                acc[rf][cf] = __builtin_amdgcn_mfma_f32_16x16x32_bf16(ah[rf], bl, acc[rf][cf], 0, 0, 0);
                acc[rf][cf] = __builtin_amdgcn_mfma_f32_16x16x32_bf16(al[rf], bh, acc[rf][cf], 0, 0, 0);
            }
        }
    }

    float bb[8];
#pragma unroll
    for (int cf = 0; cf < 8; ++cf) {
        int c = col0 + cf * 16 + l15;
        bb[cf] = (BIAS && c < ncol) ? bias[c] : 0.f;
    }

#pragma unroll
    for (int rf = 0; rf < 2; ++rf) {
#pragma unroll
        for (int r = 0; r < 4; ++r) {
            const int row = rowbase + rf * 16 + lq * 4 + r;
            if (row < N_NODES) {
                const float s = SCALE ? dinv[row] : 1.f;
#pragma unroll
                for (int cf = 0; cf < 8; ++cf) {
                    const int c = col0 + cf * 16 + l15;
                    if (c < ncol) {
                        float v = acc[rf][cf][r];
                        if (SCALE) v *= s;
                        if (BIAS) v += bb[cf];
                        out[(size_t)row * ldo + c] = (OT)v;
                    }
                }
            }
        }
    }
}

// ---------------- CSR aggregation over fp16 table, fp32 accumulate ----------------
// 16 lanes per node, 16B (8 halves) per lane per edge.
template <int RELU, typename OT>
__global__ __launch_bounds__(256) void k_agg_csr(const _Float16* __restrict__ tab,
                                                 const int* __restrict__ rp,
                                                 const int* __restrict__ ss,
                                                 const float* __restrict__ dinv,
                                                 const float* __restrict__ bias,
                                                 OT* __restrict__ outp, int n) {
    int t = blockIdx.x * 256 + threadIdx.x;
    int node = t >> 4;
    int q = (t & 15) * 8;                 // half index within the 128-wide row
    if (node >= n) return;
    int beg = rp[node], end = rp[node + 1];
    float a[8] = {};
    int i = beg;
    for (; i + 2 <= end; i += 2) {
        int s0 = ss[i], s1 = ss[i + 1];
        h8 v0 = *(const h8*)(tab + (size_t)s0 * HID_DIM + q);
        h8 v1 = *(const h8*)(tab + (size_t)s1 * HID_DIM + q);
#pragma unroll
        for (int j = 0; j < 8; ++j) a[j] += (float)v0[j] + (float)v1[j];
    }
    if (i < end) {
        int s0 = ss[i];
        h8 v0 = *(const h8*)(tab + (size_t)s0 * HID_DIM + q);
#pragma unroll
        for (int j = 0; j < 8; ++j) a[j] += (float)v0[j];
    }
    h8 own = *(const h8*)(tab + (size_t)node * HID_DIM + q);
    float s = dinv[node];
    if constexpr (RELU) {
        float4 b0 = *(const float4*)(bias + q);
        float4 b1 = *(const float4*)(bias + q + 4);
        float bb[8] = {b0.x, b0.y, b0.z, b0.w, b1.x, b1.y, b1.z, b1.w};
        h8 r;
#pragma unroll
        for (int j = 0; j < 8; ++j)
            r[j] = (_Float16)(fmaxf(fmaf(s, a[j] + (float)own[j], bb[j]), 0.f) * s);
        *(h8*)((_Float16*)outp + (size_t)node * HID_DIM + q) = r;
    } else if constexpr (sizeof(OT) == 2) {
        h8 r;
#pragma unroll
        for (int j = 0; j < 8; ++j) r[j] = (_Float16)(s * (a[j] + (float)own[j]));
        *(h8*)((_Float16*)outp + (size_t)node * HID_DIM + q) = r;
    } else {
        float* op = (float*)outp + (size_t)node * HID_DIM + q;
        float4 r0, r1;
        r0.x = s * (a[0] + (float)own[0]);
        r0.y = s * (a[1] + (float)own[1]);
        r0.z = s * (a[2] + (float)own[2]);
        r0.w = s * (a[3] + (float)own[3]);
        r1.x = s * (a[4] + (float)own[4]);
        r1.y = s * (a[5] + (float)own[5]);
        r1.z = s * (a[6] + (float)own[6]);
        r1.w = s * (a[7] + (float)own[7]);
        *(float4*)op = r0;
        *(float4*)(op + 4) = r1;
    }
}

// ---------------- GEMM2 fp32 fallback (used only if ws too small for W2 frags) ----------------
__global__ __launch_bounds__(256) void k_gemm2(const float* __restrict__ A2,
                                               const float* __restrict__ W2,
                                               const float* __restrict__ b2,
                                               float* __restrict__ out) {
    __shared__ float As[16 * 132];
    __shared__ float Bs[16 * 128];
    const int tid = threadIdx.x;
    const int tx = tid & 15, ty = tid >> 4;
    const int row0 = blockIdx.x * 128;
    const int col0 = blockIdx.y * 128;

    const int ar = tid >> 2;
    const int ak = (tid & 3) * 4;
    const int bk = tid >> 5;
    const int bc = (tid & 31) * 4;

    float acc[8][8] = {};

    for (int k0 = 0; k0 < HID_DIM; k0 += 16) {
        float4 a0 = make_float4(0.f, 0.f, 0.f, 0.f), a1 = a0;
        const int r0 = row0 + ar, r1 = row0 + ar + 64;
        if (r0 < N_NODES) a0 = *(const float4*)(A2 + (size_t)r0 * HID_DIM + k0 + ak);
        if (r1 < N_NODES) a1 = *(const float4*)(A2 + (size_t)r1 * HID_DIM + k0 + ak);
        float bv0[4], bv1[4];
#pragma unroll
        for (int j = 0; j < 4; ++j) {
            int c = col0 + bc + j;
            bv0[j] = (c < OUT_DIM) ? W2[(size_t)(k0 + bk) * OUT_DIM + c] : 0.f;
            bv1[j] = (c < OUT_DIM) ? W2[(size_t)(k0 + bk + 8) * OUT_DIM + c] : 0.f;
        }
        __syncthreads();
        As[(ak + 0) * 132 + ar] = a0.x;
        As[(ak + 1) * 132 + ar] = a0.y;
        As[(ak + 2) * 132 + ar] = a0.z;
        As[(ak + 3) * 132 + ar] = a0.w;
        As[(ak + 0) * 132 + ar + 64] = a1.x;
        As[(ak + 1) * 132 + ar + 64] = a1.y;
        As[(ak + 2) * 132 + ar + 64] = a1.z;
        As[(ak + 3) * 132 + ar + 64] = a1.w;
#pragma unroll
        for (int j = 0; j < 4; ++j) {
            Bs[bk * 128 + bc + j] = bv0[j];
            Bs[(bk + 8) * 128 + bc + j] = bv1[j];
        }
        __syncthreads();
#pragma unroll
        for (int kk = 0; kk < 16; ++kk) {
            float4 A0 = *(const float4*)(As + kk * 132 + ty * 4);
            float4 A1 = *(const float4*)(As + kk * 132 + 64 + ty * 4);
            float4 B0 = *(const float4*)(Bs + kk * 128 + tx * 4);
            float4 B1 = *(const float4*)(Bs + kk * 128 + 64 + tx * 4);
            float a_[8] = {A0.x, A0.y, A0.z, A0.w, A1.x, A1.y, A1.z, A1.w};
            float b_[8] = {B0.x, B0.y, B0.z, B0.w, B1.x, B1.y, B1.z, B1.w};
#pragma unroll
            for (int i = 0; i < 8; ++i)
#pragma unroll
                for (int j = 0; j < 8; ++j)
                    acc[i][j] = fmaf(a_[i], b_[j], acc[i][j]);
        }
    }
#pragma unroll
    for (int i = 0; i < 8; ++i) {
        const int r = row0 + ty * 4 + (i & 3) + (i >> 2) * 64;
        if (r < N_NODES) {
#pragma unroll
            for (int j = 0; j < 8; ++j) {
                int c = col0 + tx * 4 + (j & 3) + (j >> 2) * 64;
                if (c < OUT_DIM) out[(size_t)r * OUT_DIM + c] = acc[i][j] + b2[c];
            }
        }
    }
}

extern "C" void kernel_launch(void* const* d_in, const int* in_sizes, int n_in,
                              void* d_out, int out_size, void* d_ws, size_t ws_size,
                              hipStream_t stream) {
    const float* x  = (const float*)d_in[0];
    const int*   ei = (const int*)d_in[1];
    const float* W1 = (const float*)d_in[2];
    const float* b1 = (const float*)d_in[3];
    const float* W2 = (const float*)d_in[4];
    const float* b2 = (const float*)d_in[5];
    float* out = (float*)d_out;

    const int E = in_sizes[1] / 2;
    const int* src = ei;
    const int* dst = ei + E;

    // ws: hs (layer-1 fp16 features, 25.6 MB) / A2 alias at base.
    _Float16* hs = (_Float16*)d_ws;
    _Float16* A2h = hs;
    float* A2f = (float*)d_ws;                         // fp32 fallback only

    const int NB1 = (E + EPB - 1) / EPB;               // 391

    // d_out scratch (all dead before the final out-writer):
    char* ob = (char*)d_out;
    size_t o = (size_t)N_NODES * HID_DIM * 2;          // h2 fp16: 25.6 MB
    _Float16* h2 = (_Float16*)ob;
    float* dinv = (float*)(ob + o); o += 400128;
    int* bcnt = (int*)(ob + o); o += 1024;             // NBKT ints
    int* rp   = (int*)(ob + o); o += 400640;           // (N+1) ints padded
    int* gbase = (int*)(ob + o); o += 1024;            // NBKT+1 ints
    int* gcur  = (int*)(ob + o); o += 1024;
    int* ss   = (int*)(ob + o); o += (size_t)E * 4;    // 6.4 MB
    unsigned* pairs = (unsigned*)(ob + o); o += (size_t)E * 4;   // 6.4 MB (packed)
    int* hcnt = (int*)(ob + o); o += (size_t)NB1 * NBKT * 4;     // per-block histograms
    // W1 fragments: dead before the final out-writes (only read by gemm1)
    unsigned short* W1h = (unsigned short*)(ob + o); o += 65536;
    unsigned short* W1l = (unsigned short*)(ob + o); o += 65536;

    // W2 fragments MUST NOT live in d_out (gemm2 reads them while writing out).
    const size_t W2OFF = 32u << 20;
    const bool w2frag = ws_size >= W2OFF + 131072;
    unsigned short* W2h = (unsigned short*)((char*)d_ws + W2OFF);
    unsigned short* W2l = W2h + 32768;

    k_wsplit<<<128, 256, 0, stream>>>(W1, W1h, W1l, IN_DIM, HID_DIM, HID_DIM);
    if (w2frag)
        k_wsplit<<<128, 256, 0, stream>>>(W2, W2h, W2l, HID_DIM, OUT_DIM, 256);

    hipMemsetAsync(bcnt, 0, 1024, stream);
    k_bhist<<<NB1, 256, 0, stream>>>(dst, bcnt, hcnt, E);
    k_bscan<<<1, 256, 0, stream>>>(bcnt, gbase, gcur, E);
    k_part1<<<NB1, 256, 0, stream>>>(src, dst, hcnt, gcur, pairs, E);
    k_bucket_csr<<<NBKT, 256, 0, stream>>>(pairs, gbase, rp, dinv, ss, N_NODES, E);

    // GEMM1: hs = (X @ W1) * dinv[row]  — bf16x3 MFMA, fp16 output (r2 config)
    dim3 g1((N_NODES + 127) / 128, 1);
    k_gemm_mfma<float, _Float16, IN_DIM, HID_DIM, 1, 0><<<g1, 256, 0, stream>>>(
        x, W1h, W1l, dinv, nullptr, hs, HID_DIM, HID_DIM);

    const int aggBlocks = (N_NODES * 16 + 255) / 256;
    k_agg_csr<1, _Float16><<<aggBlocks, 256, 0, stream>>>(hs, rp, ss, dinv, b1, h2, N_NODES);

    if (w2frag) {
        k_agg_csr<0, _Float16><<<aggBlocks, 256, 0, stream>>>(h2, rp, ss, dinv, b1, A2h, N_NODES);
        // GEMM2: out = A2 @ W2 + b2 — bf16x3 MFMA (fp16 A splits exactly), cols padded to 256
        dim3 g2((N_NODES + 127) / 128, 2);
        k_gemm_mfma<_Float16, float, HID_DIM, 256, 0, 1><<<g2, 256, 0, stream>>>(
            A2h, W2h, W2l, nullptr, b2, out, OUT_DIM, OUT_DIM);
    } else {
        k_agg_csr<0, float><<<aggBlocks, 256, 0, stream>>>(h2, rp, ss, dinv, b1, A2f, N_NODES);
        dim3 g2((N_NODES + 127) / 128, (OUT_DIM + 127) / 128);
        k_gemm2<<<g2, 256, 0, stream>>>(A2f, W2, b2, out);
    }
}